// Round 1
// baseline (744.075 us; speedup 1.0000x reference)
//
#include <hip/hip_runtime.h>
#include <cstdint>

#define NSI   100000
#define NM    100000
#define NINT  500000
#define NEDGE 500000

// ---------------- workspace layout (float offsets) ----------------
static const long OFF_WSI  = 0;                       // [128][64] cat: cols 0-31 W1l_si2i, 32-63 W1l_si+W1r_si
static const long OFF_WM   = 8192;                    // [128][64] same for m
static const long OFF_WI   = 16384;                   // [64][32] 0.5*(W1r_si2i+W1r_m2i)
static const long OFF_USI  = 18432;                   // [32] W2l_si2i @ wlin
static const long OFF_UM   = 18464;                   // [32]
static const long OFF_V    = 18496;                   // [32] 0.5*(W2r_si2i+W2r_m2i) @ wlin
static const long OFF_C0   = 18528;                   // [1] scalar bias, pad to 32
static const long OFF_PSI  = 18560;                   // [NSI][32] x_si @ W1l_si2i
static const long OFF_HSI  = OFF_PSI + 3200000;       // [NSI][32] relu(x_si@(W1l+W1r)+b)
static const long OFF_PM   = OFF_HSI + 3200000;
static const long OFF_HM   = OFF_PM + 3200000;
static const long OFF_SSI  = OFF_HM + 3200000;        // [NSI] scalar per src node (layer2)
static const long OFF_SM   = OFF_SSI + 100000;
static const long OFF_RI   = OFF_SM + 100000;         // [NINT][32] x_int@Wi + 0.5*(b1+b1)
static const long OFF_ACCS = OFF_RI + 16000000;       // ---- zero region start ----
static const long OFF_ACCM = OFF_ACCS + 16000000;
static const long OFF_CS   = OFF_ACCM + 16000000;     // [NINT] counts
static const long OFF_CM   = OFF_CS + 500000;
static const long OFF_SAS  = OFF_CM + 500000;         // [NINT] layer2 scalar acc
static const long OFF_SAM  = OFF_SAS + 500000;
static const long OFF_END  = OFF_SAM + 500000;        // 63,018,560 floats = 252 MB

// ---------------- prep: combined weight tensors ----------------
__global__ __launch_bounds__(256) void prep_kernel(
    const float* __restrict__ W1l_si2i, const float* __restrict__ W1l_si, const float* __restrict__ W1r_si,
    const float* __restrict__ W1l_m2i,  const float* __restrict__ W1l_m,  const float* __restrict__ W1r_m,
    const float* __restrict__ W1r_si2i, const float* __restrict__ W1r_m2i,
    const float* __restrict__ W2l_si2i, const float* __restrict__ W2l_m2i,
    const float* __restrict__ W2r_si2i, const float* __restrict__ W2r_m2i,
    const float* __restrict__ b2_si2i,  const float* __restrict__ b2_m2i,
    const float* __restrict__ Wlin,     const float* __restrict__ blin,
    float* __restrict__ Wsi, float* __restrict__ Wm, float* __restrict__ Wi,
    float* __restrict__ u_si, float* __restrict__ u_m, float* __restrict__ v, float* __restrict__ c0)
{
    const int tid = threadIdx.x;
    for (int idx = tid; idx < 128 * 64; idx += 256) {
        int k = idx >> 6, c = idx & 63;
        float a, b;
        if (c < 32) { a = W1l_si2i[k * 32 + c];      b = W1l_m2i[k * 32 + c]; }
        else { int cc = c - 32;
               a = W1l_si[k * 32 + cc] + W1r_si[k * 32 + cc];
               b = W1l_m[k * 32 + cc]  + W1r_m[k * 32 + cc]; }
        Wsi[idx] = a; Wm[idx] = b;
    }
    for (int idx = tid; idx < 64 * 32; idx += 256)
        Wi[idx] = 0.5f * (W1r_si2i[idx] + W1r_m2i[idx]);
    if (tid < 32) {
        float us = 0.f, um = 0.f, vv = 0.f;
        for (int k = 0; k < 16; ++k) {
            float wl = Wlin[k];
            us += W2l_si2i[tid * 16 + k] * wl;
            um += W2l_m2i[tid * 16 + k] * wl;
            vv += 0.5f * (W2r_si2i[tid * 16 + k] + W2r_m2i[tid * 16 + k]) * wl;
        }
        u_si[tid] = us; u_m[tid] = um; v[tid] = vv;
    }
    if (tid == 0) {
        float c = blin[0];
        for (int k = 0; k < 16; ++k) c += 0.5f * (b2_si2i[k] + b2_m2i[k]) * Wlin[k];
        c0[0] = c;
    }
}

// ---------------- GEMM for src node types: K=128, M=64 (P|H), 64-row tile ----------------
__global__ __launch_bounds__(256) void gemm_src(
    const float* __restrict__ X, const float* __restrict__ Wcat, const float* __restrict__ bias,
    float* __restrict__ P, float* __restrict__ H, int N)
{
    __shared__ float xs[64 * 132];   // pad 132 -> 2-way (free) b128 reads
    __shared__ float lw[64 * 64];    // half of W at a time (keeps LDS < 64 KB, 3 blocks/CU)
    const int tid = threadIdx.x;
    const long row_base = (long)blockIdx.x * 64;

    #pragma unroll
    for (int i = 0; i < 8; ++i) {
        int idx = tid + i * 256;
        int r = idx >> 5, k4 = idx & 31;
        long rr = row_base + r;
        float4 val = make_float4(0.f, 0.f, 0.f, 0.f);
        if (rr < N) val = ((const float4*)X)[rr * 32 + k4];
        *(float4*)&xs[r * 132 + k4 * 4] = val;
    }

    const int r0 = tid & 15;
    const int c0 = (tid >> 4) * 4;
    float acc[4][4] = {{0.f}};

    for (int half = 0; half < 2; ++half) {
        __syncthreads();
        #pragma unroll
        for (int i = 0; i < 4; ++i) {
            int idx = tid + i * 256;
            ((float4*)lw)[idx] = ((const float4*)Wcat)[half * 1024 + idx];
        }
        __syncthreads();
        const float* xb = xs + half * 64;
        #pragma unroll 4
        for (int k = 0; k < 64; k += 4) {
            float4 xr[4];
            #pragma unroll
            for (int j = 0; j < 4; ++j)
                xr[j] = *(const float4*)&xb[(r0 + 16 * j) * 132 + k];
            #pragma unroll
            for (int kk = 0; kk < 4; ++kk) {
                float4 wv = *(const float4*)&lw[(k + kk) * 64 + c0];
                #pragma unroll
                for (int j = 0; j < 4; ++j) {
                    float xv = (kk == 0) ? xr[j].x : (kk == 1) ? xr[j].y : (kk == 2) ? xr[j].z : xr[j].w;
                    acc[j][0] = fmaf(xv, wv.x, acc[j][0]);
                    acc[j][1] = fmaf(xv, wv.y, acc[j][1]);
                    acc[j][2] = fmaf(xv, wv.z, acc[j][2]);
                    acc[j][3] = fmaf(xv, wv.w, acc[j][3]);
                }
            }
        }
    }

    #pragma unroll
    for (int j = 0; j < 4; ++j) {
        long rr = row_base + r0 + 16 * j;
        if (rr >= N) continue;
        if (c0 < 32) {
            *(float4*)&P[rr * 32 + c0] = make_float4(acc[j][0], acc[j][1], acc[j][2], acc[j][3]);
        } else {
            const int cc = c0 - 32;
            float4 o;
            o.x = fmaxf(acc[j][0] + bias[cc + 0], 0.f);
            o.y = fmaxf(acc[j][1] + bias[cc + 1], 0.f);
            o.z = fmaxf(acc[j][2] + bias[cc + 2], 0.f);
            o.w = fmaxf(acc[j][3] + bias[cc + 3], 0.f);
            *(float4*)&H[rr * 32 + cc] = o;
        }
    }
}

// ---------------- GEMM for int nodes: K=64, M=32, 64-row tile, 128 threads ----------------
__global__ __launch_bounds__(128) void gemm_int(
    const float* __restrict__ X, const float* __restrict__ W,
    const float* __restrict__ b1a, const float* __restrict__ b1b,
    float* __restrict__ R, int N)
{
    __shared__ float xs[64 * 68];
    __shared__ float lw[64 * 32];
    const int tid = threadIdx.x;
    const long row_base = (long)blockIdx.x * 64;

    #pragma unroll
    for (int i = 0; i < 4; ++i)
        ((float4*)lw)[tid + i * 128] = ((const float4*)W)[tid + i * 128];
    #pragma unroll
    for (int i = 0; i < 8; ++i) {
        int idx = tid + i * 128;
        int r = idx >> 4, k4 = idx & 15;
        long rr = row_base + r;
        float4 val = make_float4(0.f, 0.f, 0.f, 0.f);
        if (rr < N) val = ((const float4*)X)[rr * 16 + k4];
        *(float4*)&xs[r * 68 + k4 * 4] = val;
    }
    __syncthreads();

    const int r0 = tid & 15;
    const int c0 = (tid >> 4) * 4;   // 0..28
    float acc[4][4] = {{0.f}};
    #pragma unroll 4
    for (int k = 0; k < 64; k += 4) {
        float4 xr[4];
        #pragma unroll
        for (int j = 0; j < 4; ++j)
            xr[j] = *(const float4*)&xs[(r0 + 16 * j) * 68 + k];
        #pragma unroll
        for (int kk = 0; kk < 4; ++kk) {
            float4 wv = *(const float4*)&lw[(k + kk) * 32 + c0];
            #pragma unroll
            for (int j = 0; j < 4; ++j) {
                float xv = (kk == 0) ? xr[j].x : (kk == 1) ? xr[j].y : (kk == 2) ? xr[j].z : xr[j].w;
                acc[j][0] = fmaf(xv, wv.x, acc[j][0]);
                acc[j][1] = fmaf(xv, wv.y, acc[j][1]);
                acc[j][2] = fmaf(xv, wv.z, acc[j][2]);
                acc[j][3] = fmaf(xv, wv.w, acc[j][3]);
            }
        }
    }
    #pragma unroll
    for (int j = 0; j < 4; ++j) {
        long rr = row_base + r0 + 16 * j;
        if (rr >= N) continue;
        float4 o;
        o.x = acc[j][0] + 0.5f * (b1a[c0 + 0] + b1b[c0 + 0]);
        o.y = acc[j][1] + 0.5f * (b1a[c0 + 1] + b1b[c0 + 1]);
        o.z = acc[j][2] + 0.5f * (b1a[c0 + 2] + b1b[c0 + 2]);
        o.w = acc[j][3] + 0.5f * (b1a[c0 + 3] + b1b[c0 + 3]);
        *(float4*)&R[rr * 32 + c0] = o;
    }
}

// ---------------- per-src-node layer-2 scalar: s[n] = h[n] . u ----------------
__global__ __launch_bounds__(256) void s_kernel(
    const float* __restrict__ h_si, const float* __restrict__ h_m,
    const float* __restrict__ u_si, const float* __restrict__ u_m,
    float* __restrict__ s_si, float* __restrict__ s_m)
{
    long gid = (long)blockIdx.x * 256 + threadIdx.x;
    long node = gid >> 5;
    int f = (int)(gid & 31);
    if (node >= (long)(NSI + NM)) return;
    const float* h; const float* u; float* s; long n;
    if (node < NSI) { h = h_si; u = u_si; s = s_si; n = node; }
    else            { h = h_m;  u = u_m;  s = s_m;  n = node - NSI; }
    float t = h[n * 32 + f] * u[f];
    #pragma unroll
    for (int off = 16; off > 0; off >>= 1) t += __shfl_xor(t, off);
    if (f == 0) s[n] = t;
}

// ---------------- edge scatter (one 32-lane group per edge) ----------------
__global__ __launch_bounds__(256) void scatter_kernel(
    const float* __restrict__ p, const float* __restrict__ s,
    const int* __restrict__ src, const int* __restrict__ dst,
    float* __restrict__ acc, float* __restrict__ cnt, float* __restrict__ sacc)
{
    long gid = (long)blockIdx.x * 256 + threadIdx.x;
    long e = gid >> 5;
    int f = (int)(gid & 31);
    if (e >= NEDGE) return;
    int sn = src[e], dn = dst[e];
    atomicAdd(&acc[(long)dn * 32 + f], p[(long)sn * 32 + f]);
    if (f == 0) {
        atomicAdd(&cnt[dn], 1.0f);
        atomicAdd(&sacc[dn], s[sn]);
    }
}

// ---------------- fused h_int + layer2 + readout ----------------
__global__ __launch_bounds__(256) void final_kernel(
    const float* __restrict__ r_int,
    const float* __restrict__ acc_si, const float* __restrict__ acc_m,
    const float* __restrict__ cnt_si, const float* __restrict__ cnt_m,
    const float* __restrict__ sacc_si, const float* __restrict__ sacc_m,
    const float* __restrict__ v, const float* __restrict__ c0,
    float* __restrict__ out)
{
    long gid = (long)blockIdx.x * 256 + threadIdx.x;
    long node = gid >> 5;
    int f = (int)(gid & 31);
    if (node >= NINT) return;
    float csi = fmaxf(cnt_si[node], 1.0f);
    float cm  = fmaxf(cnt_m[node],  1.0f);
    long base = node * 32 + f;
    float h = r_int[base] + 0.5f * (acc_si[base] / csi + acc_m[base] / cm);
    h = fmaxf(h, 0.0f);
    float t = h * v[f];
    #pragma unroll
    for (int off = 16; off > 0; off >>= 1) t += __shfl_xor(t, off);
    if (f == 0)
        out[node] = t + 0.5f * (sacc_si[node] / csi + sacc_m[node] / cm) + c0[0];
}

extern "C" void kernel_launch(void* const* d_in, const int* in_sizes, int n_in,
                              void* d_out, int out_size, void* d_ws, size_t ws_size,
                              hipStream_t stream)
{
    const float* x_si     = (const float*)d_in[0];
    const float* x_m      = (const float*)d_in[1];
    const float* x_int    = (const float*)d_in[2];
    const float* W1l_si2i = (const float*)d_in[3];
    const float* W1r_si2i = (const float*)d_in[4];
    const float* b1_si2i  = (const float*)d_in[5];
    const float* W1l_m2i  = (const float*)d_in[6];
    const float* W1r_m2i  = (const float*)d_in[7];
    const float* b1_m2i   = (const float*)d_in[8];
    const float* W1l_si   = (const float*)d_in[9];
    const float* W1r_si   = (const float*)d_in[10];
    const float* b1_si    = (const float*)d_in[11];
    const float* W1l_m    = (const float*)d_in[12];
    const float* W1r_m    = (const float*)d_in[13];
    const float* b1_m     = (const float*)d_in[14];
    const float* W2l_si2i = (const float*)d_in[15];
    const float* W2r_si2i = (const float*)d_in[16];
    const float* b2_si2i  = (const float*)d_in[17];
    const float* W2l_m2i  = (const float*)d_in[18];
    const float* W2r_m2i  = (const float*)d_in[19];
    const float* b2_m2i   = (const float*)d_in[20];
    // d_in[21..26] (W2*_si / W2*_m / b2_si / b2_m) do not reach the output — unused
    const float* Wlin     = (const float*)d_in[27];
    const float* blin     = (const float*)d_in[28];
    const int* src_si2i   = (const int*)d_in[29];
    const int* dst_si2i   = (const int*)d_in[30];
    const int* src_m2i    = (const int*)d_in[31];
    const int* dst_m2i    = (const int*)d_in[32];

    float* ws = (float*)d_ws;
    if (ws_size < (size_t)OFF_END * sizeof(float)) return;  // insufficient scratch -> loud failure

    prep_kernel<<<1, 256, 0, stream>>>(
        W1l_si2i, W1l_si, W1r_si, W1l_m2i, W1l_m, W1r_m,
        W1r_si2i, W1r_m2i, W2l_si2i, W2l_m2i, W2r_si2i, W2r_m2i,
        b2_si2i, b2_m2i, Wlin, blin,
        ws + OFF_WSI, ws + OFF_WM, ws + OFF_WI,
        ws + OFF_USI, ws + OFF_UM, ws + OFF_V, ws + OFF_C0);

    hipMemsetAsync(ws + OFF_ACCS, 0, (size_t)(OFF_END - OFF_ACCS) * sizeof(float), stream);

    gemm_src<<<(NSI + 63) / 64, 256, 0, stream>>>(x_si, ws + OFF_WSI, b1_si, ws + OFF_PSI, ws + OFF_HSI, NSI);
    gemm_src<<<(NM  + 63) / 64, 256, 0, stream>>>(x_m,  ws + OFF_WM,  b1_m,  ws + OFF_PM,  ws + OFF_HM,  NM);
    gemm_int<<<(NINT + 63) / 64, 128, 0, stream>>>(x_int, ws + OFF_WI, b1_si2i, b1_m2i, ws + OFF_RI, NINT);

    s_kernel<<<(NSI + NM) / 8, 256, 0, stream>>>(ws + OFF_HSI, ws + OFF_HM,
                                                 ws + OFF_USI, ws + OFF_UM,
                                                 ws + OFF_SSI, ws + OFF_SM);

    scatter_kernel<<<(NEDGE * 32) / 256, 256, 0, stream>>>(ws + OFF_PSI, ws + OFF_SSI, src_si2i, dst_si2i,
                                                           ws + OFF_ACCS, ws + OFF_CS, ws + OFF_SAS);
    scatter_kernel<<<(NEDGE * 32) / 256, 256, 0, stream>>>(ws + OFF_PM, ws + OFF_SM, src_m2i, dst_m2i,
                                                           ws + OFF_ACCM, ws + OFF_CM, ws + OFF_SAM);

    final_kernel<<<(NINT * 32) / 256, 256, 0, stream>>>(ws + OFF_RI, ws + OFF_ACCS, ws + OFF_ACCM,
                                                        ws + OFF_CS, ws + OFF_CM, ws + OFF_SAS, ws + OFF_SAM,
                                                        ws + OFF_V, ws + OFF_C0, (float*)d_out);
}